// Round 3
// baseline (29639.700 us; speedup 1.0000x reference)
//
#include <hip/hip_runtime.h>
#include <hip/hip_bf16.h>
#include <cstdint>

#define BATCH 64
#define SEQ   512
#define DIM   512
#define MTOT  (BATCH*SEQ)   // 32768

// W_hh residency split in j4-blocks (4 j-rows x 512 cols = 8 KB each; 128 total)
#define RB 32               // register-resident blocks (j 0..127)   -> 128 VGPRs/thread
#define LB 19               // LDS-resident blocks     (j 128..203)  -> 152 KB
#define SBASE (RB + LB)     // first streamed block (51); 77 streamed = 616 KB/step
// dynamic LDS: h0(2KB) + h1(2KB) + wlds(152KB) = 159744 B (opt-in >64KB)
#define RNN_LDS_BYTES ((2 * (DIM / 4) + LB * DIM) * 16)

// ---------------------------------------------------------------------------
// Kernel 0: pack W_hh [c][j] -> Wpk[jb][c] (float4 over j%4)
// ---------------------------------------------------------------------------
__global__ __launch_bounds__(128) void pack_w(const float* __restrict__ W,
                                              float4* __restrict__ Wpk) {
    const int c  = blockIdx.x;
    const int jb = threadIdx.x;
    const float4 v = *(const float4*)&W[(size_t)c * DIM + 4 * jb];
    Wpk[(size_t)jb * DIM + c] = v;
}

// ---------------------------------------------------------------------------
// Kernel 1: fused embedding gather + input projection (NT GEMM, fp32)
// ---------------------------------------------------------------------------
__global__ __launch_bounds__(256) void embed_proj(
    const int*   __restrict__ xidx,
    const float* __restrict__ emb,
    const float* __restrict__ W_ih,
    const float* __restrict__ b_ih,
    const float* __restrict__ b_hh,
    float*       __restrict__ xp) {
    __shared__ float As[64][68];  // As[k][m]
    __shared__ float Bs[64][68];  // Bs[k][n]

    const int m0  = blockIdx.x * 64;
    const int n0  = blockIdx.y * 64;
    const int tid = threadIdx.x;

    const int lr = tid >> 4;
    const int lc = (tid & 15) << 2;

    int rows[4];
#pragma unroll
    for (int i = 0; i < 4; i++) rows[i] = xidx[m0 + lr + 16 * i];

    const int tm = (tid & 15) << 2;
    const int tn = (tid >> 4) << 2;

    float acc[4][4];
#pragma unroll
    for (int i = 0; i < 4; i++)
#pragma unroll
        for (int j = 0; j < 4; j++) acc[i][j] = 0.0f;

    for (int k0 = 0; k0 < DIM; k0 += 64) {
#pragma unroll
        for (int i = 0; i < 4; i++) {
            const int rl = lr + 16 * i;
            const float4 a = *(const float4*)&emb[(size_t)rows[i] * DIM + k0 + lc];
            As[lc + 0][rl] = a.x; As[lc + 1][rl] = a.y;
            As[lc + 2][rl] = a.z; As[lc + 3][rl] = a.w;
            const float4 b = *(const float4*)&W_ih[(size_t)(n0 + rl) * DIM + k0 + lc];
            Bs[lc + 0][rl] = b.x; Bs[lc + 1][rl] = b.y;
            Bs[lc + 2][rl] = b.z; Bs[lc + 3][rl] = b.w;
        }
        __syncthreads();
#pragma unroll 8
        for (int kk = 0; kk < 64; kk++) {
            const float4 a = *(const float4*)&As[kk][tm];
            const float4 b = *(const float4*)&Bs[kk][tn];
            acc[0][0] = fmaf(a.x, b.x, acc[0][0]);
            acc[0][1] = fmaf(a.x, b.y, acc[0][1]);
            acc[0][2] = fmaf(a.x, b.z, acc[0][2]);
            acc[0][3] = fmaf(a.x, b.w, acc[0][3]);
            acc[1][0] = fmaf(a.y, b.x, acc[1][0]);
            acc[1][1] = fmaf(a.y, b.y, acc[1][1]);
            acc[1][2] = fmaf(a.y, b.z, acc[1][2]);
            acc[1][3] = fmaf(a.y, b.w, acc[1][3]);
            acc[2][0] = fmaf(a.z, b.x, acc[2][0]);
            acc[2][1] = fmaf(a.z, b.y, acc[2][1]);
            acc[2][2] = fmaf(a.z, b.z, acc[2][2]);
            acc[2][3] = fmaf(a.z, b.w, acc[2][3]);
            acc[3][0] = fmaf(a.w, b.x, acc[3][0]);
            acc[3][1] = fmaf(a.w, b.y, acc[3][1]);
            acc[3][2] = fmaf(a.w, b.z, acc[3][2]);
            acc[3][3] = fmaf(a.w, b.w, acc[3][3]);
        }
        __syncthreads();
    }

    const int n = n0 + tn;
    const float bias0 = b_ih[n + 0] + b_hh[n + 0];
    const float bias1 = b_ih[n + 1] + b_hh[n + 1];
    const float bias2 = b_ih[n + 2] + b_hh[n + 2];
    const float bias3 = b_ih[n + 3] + b_hh[n + 3];
#pragma unroll
    for (int i = 0; i < 4; i++) {
        float4 o;
        o.x = acc[i][0] + bias0;
        o.y = acc[i][1] + bias1;
        o.z = acc[i][2] + bias2;
        o.w = acc[i][3] + bias3;
        *(float4*)&xp[(size_t)(m0 + tm + i) * DIM + n] = o;
    }
}

// ---------------------------------------------------------------------------
// Kernel 2: sequential RNN scan, W mostly resident on-CU.
//  32 wgs x 512 threads; wg = batch rows (2*blk, 2*blk+1); thread = column tid.
//  W split: 128 j-rows in VGPRs (128 regs), 76 in LDS (152 KB), 308 streamed.
//  amdgpu_waves_per_eu(2,2): pins allocator budget to 256 VGPRs (8-wave block
//  = exactly 2 waves/EU) — launch_bounds(512,2) made it spill at 128 (R2).
// ---------------------------------------------------------------------------
__global__ __launch_bounds__(512)
__attribute__((amdgpu_waves_per_eu(2, 2)))
void rnn_scan(const float4* __restrict__ Wpk, float* __restrict__ buf) {
    extern __shared__ float4 smem[];
    float4* h0s  = smem;                 // [128] h row b0
    float4* h1s  = smem + DIM / 4;       // [128] h row b0+1
    float4* wlds = smem + 2 * (DIM / 4); // [LB*DIM] W blocks RB..RB+LB-1

    const int tid = threadIdx.x;
    const int b0  = blockIdx.x * 2;

    // register-resident W: j4-blocks 0..RB-1, this thread's column
    float4 wreg[RB];
#pragma unroll
    for (int i = 0; i < RB; i++) wreg[i] = Wpk[(size_t)i * DIM + tid];

    // LDS-resident W: j4-blocks RB..RB+LB-1
    for (int i = 0; i < LB; i++) wlds[i * DIM + tid] = Wpk[(size_t)(RB + i) * DIM + tid];

    ((float*)h0s)[tid] = 0.0f;
    ((float*)h1s)[tid] = 0.0f;
    __syncthreads();

    float* row0 = buf + (size_t)b0 * SEQ * DIM;
    float* row1 = buf + (size_t)(b0 + 1) * SEQ * DIM;

    for (int t = 0; t < SEQ; t++) {
        const int off = t * DIM + tid;
        float4 a0 = make_float4(0.f, 0.f, 0.f, 0.f);
        float4 a1 = make_float4(0.f, 0.f, 0.f, 0.f);
        const float x0 = row0[off];
        const float x1 = row1[off];

        // ---- streamed: blocks SBASE..127, batches of 7 loads for MLP ----
        for (int g = 0; g < 77; g += 7) {
            float4 wv[7];
#pragma unroll
            for (int u = 0; u < 7; u++)
                wv[u] = Wpk[(size_t)(SBASE + g + u) * DIM + tid];
#pragma unroll
            for (int u = 0; u < 7; u++) {
                const float4 ha = h0s[SBASE + g + u];
                const float4 hb = h1s[SBASE + g + u];
                a0.x = fmaf(wv[u].x, ha.x, a0.x); a0.y = fmaf(wv[u].y, ha.y, a0.y);
                a0.z = fmaf(wv[u].z, ha.z, a0.z); a0.w = fmaf(wv[u].w, ha.w, a0.w);
                a1.x = fmaf(wv[u].x, hb.x, a1.x); a1.y = fmaf(wv[u].y, hb.y, a1.y);
                a1.z = fmaf(wv[u].z, hb.z, a1.z); a1.w = fmaf(wv[u].w, hb.w, a1.w);
            }
        }

        // ---- register-resident ----
#pragma unroll
        for (int i = 0; i < RB; i++) {
            const float4 wv = wreg[i];
            const float4 ha = h0s[i];
            const float4 hb = h1s[i];
            a0.x = fmaf(wv.x, ha.x, a0.x); a0.y = fmaf(wv.y, ha.y, a0.y);
            a0.z = fmaf(wv.z, ha.z, a0.z); a0.w = fmaf(wv.w, ha.w, a0.w);
            a1.x = fmaf(wv.x, hb.x, a1.x); a1.y = fmaf(wv.y, hb.y, a1.y);
            a1.z = fmaf(wv.z, hb.z, a1.z); a1.w = fmaf(wv.w, hb.w, a1.w);
        }

        // ---- LDS-resident ----
#pragma unroll 4
        for (int i = 0; i < LB; i++) {
            const float4 wv = wlds[i * DIM + tid];
            const float4 ha = h0s[RB + i];
            const float4 hb = h1s[RB + i];
            a0.x = fmaf(wv.x, ha.x, a0.x); a0.y = fmaf(wv.y, ha.y, a0.y);
            a0.z = fmaf(wv.z, ha.z, a0.z); a0.w = fmaf(wv.w, ha.w, a0.w);
            a1.x = fmaf(wv.x, hb.x, a1.x); a1.y = fmaf(wv.y, hb.y, a1.y);
            a1.z = fmaf(wv.z, hb.z, a1.z); a1.w = fmaf(wv.w, hb.w, a1.w);
        }

        const float pre0 = x0 + ((a0.x + a0.y) + (a0.z + a0.w));
        const float pre1 = x1 + ((a1.x + a1.y) + (a1.z + a1.w));
        const float hn0 = tanhf(pre0);
        const float hn1 = tanhf(pre1);

        __syncthreads();            // all h reads done before overwrite
        ((float*)h0s)[tid] = hn0;
        ((float*)h1s)[tid] = hn1;
        row0[off] = hn0;
        row1[off] = hn1;
        __syncthreads();            // h visible before next step
    }
}

// ---------------------------------------------------------------------------
// Kernel 3: softmax over H (per b,t) + transpose [B][T][H] -> out [B][H][T]
// ---------------------------------------------------------------------------
__global__ __launch_bounds__(256) void softmax_T(const float* __restrict__ hid,
                                                 float* __restrict__ out) {
    __shared__ float rowmax[64];
    __shared__ float rowinv[64];
    __shared__ float tile[64][65];

    const int b   = blockIdx.x;
    const int t0  = blockIdx.y * 64;
    const int tid = threadIdx.x;
    const float* base = hid + ((size_t)b * SEQ + t0) * DIM;

    const int r = tid >> 2;
    const int p = tid & 3;

    float m = -1e30f;
#pragma unroll 4
    for (int k = 0; k < 32; k++) {
        const float4 v = *(const float4*)&base[r * DIM + ((k * 4 + p) << 2)];
        m = fmaxf(m, fmaxf(fmaxf(v.x, v.y), fmaxf(v.z, v.w)));
    }
    m = fmaxf(m, __shfl_xor(m, 1));
    m = fmaxf(m, __shfl_xor(m, 2));

    float s = 0.0f;
#pragma unroll 4
    for (int k = 0; k < 32; k++) {
        const float4 v = *(const float4*)&base[r * DIM + ((k * 4 + p) << 2)];
        s += expf(v.x - m) + expf(v.y - m) + expf(v.z - m) + expf(v.w - m);
    }
    s += __shfl_xor(s, 1);
    s += __shfl_xor(s, 2);
    if (p == 0) {
        rowmax[r] = m;
        rowinv[r] = 1.0f / s;
    }
    __syncthreads();

    for (int hc = 0; hc < 8; hc++) {
#pragma unroll
        for (int i = 0; i < 16; i++) {
            const int lin = tid + 256 * i;
            const int rr  = lin >> 6;
            const int cc  = lin & 63;
            const float v = base[rr * DIM + hc * 64 + cc];
            tile[cc][rr] = expf(v - rowmax[rr]) * rowinv[rr];
        }
        __syncthreads();
#pragma unroll
        for (int i = 0; i < 16; i++) {
            const int lin = tid + 256 * i;
            const int hh  = lin >> 6;
            const int tt  = lin & 63;
            out[((size_t)b * DIM + hc * 64 + hh) * SEQ + t0 + tt] = tile[hh][tt];
        }
        __syncthreads();
    }
}

// ---------------------------------------------------------------------------
extern "C" void kernel_launch(void* const* d_in, const int* in_sizes, int n_in,
                              void* d_out, int out_size, void* d_ws, size_t ws_size,
                              hipStream_t stream) {
    const int*   x    = (const int*)  d_in[0];
    const float* emb  = (const float*)d_in[1];
    const float* W_ih = (const float*)d_in[2];
    const float* W_hh = (const float*)d_in[3];
    const float* b_ih = (const float*)d_in[4];
    const float* b_hh = (const float*)d_in[5];
    float* out = (float*)d_out;

    // 64 MB scratch: xp (then hid, in place) as [B][T][H]
    float* buf = (float*)d_ws;
    // packed W_hh staged in d_out (1 M floats << out_size); consumed by
    // rnn_scan before softmax_T overwrites d_out (stream-ordered).
    float4* Wpk = (float4*)out;

    // opt-in >64KB dynamic LDS for rnn_scan (host-side, idempotent, capture-safe)
    static bool attr_set = false;
    if (!attr_set) {
        hipFuncSetAttribute((const void*)rnn_scan,
                            hipFuncAttributeMaxDynamicSharedMemorySize,
                            RNN_LDS_BYTES);
        attr_set = true;
    }

    pack_w<<<dim3(DIM), 128, 0, stream>>>(W_hh, Wpk);
    embed_proj<<<dim3(MTOT / 64, DIM / 64), 256, 0, stream>>>(x, emb, W_ih, b_ih, b_hh, buf);
    rnn_scan<<<32, 512, RNN_LDS_BYTES, stream>>>(Wpk, buf);
    softmax_T<<<dim3(BATCH, SEQ / 64), 256, 0, stream>>>(buf, out);
}

// Round 4
// 10697.776 us; speedup vs baseline: 2.7706x; 2.7706x over previous
//
#include <hip/hip_runtime.h>
#include <hip/hip_bf16.h>
#include <cstdint>

#define BATCH 64
#define SEQ   512
#define DIM   512
#define MTOT  (BATCH*SEQ)   // 32768

// RNN decomposition: 8 column-slices x 16 batch-groups (4 rows each) = 128 wgs.
#define CSL 8     // column slices (64 cols each; W slice = 128 KB, LDS-resident)
#define GRP 16    // batch groups
#define RPG 4     // rows per group
// dynamic LDS: wlds 8192 float4 (128KB) + h 2048 f (8KB) + part 2048 f (8KB)
#define RNN_LDS_BYTES (8192*16 + 2048*4 + 2048*4)   // 147456

// ---------------------------------------------------------------------------
// Kernel 0: pack W_hh [c][j] -> Wpk[jb][c] (float4 over j%4); zero barriers.
// ---------------------------------------------------------------------------
__global__ __launch_bounds__(128) void pack_w(const float* __restrict__ W,
                                              float4* __restrict__ Wpk,
                                              int* __restrict__ cnt) {
    const int c  = blockIdx.x;
    const int jb = threadIdx.x;
    const float4 v = *(const float4*)&W[(size_t)c * DIM + 4 * jb];
    Wpk[(size_t)jb * DIM + c] = v;
    if (blockIdx.x == 0 && threadIdx.x < GRP) cnt[threadIdx.x] = 0;
}

// ---------------------------------------------------------------------------
// Kernel 1: fused embedding gather + input projection (NT GEMM, fp32)
// ---------------------------------------------------------------------------
__global__ __launch_bounds__(256) void embed_proj(
    const int*   __restrict__ xidx,
    const float* __restrict__ emb,
    const float* __restrict__ W_ih,
    const float* __restrict__ b_ih,
    const float* __restrict__ b_hh,
    float*       __restrict__ xp) {
    __shared__ float As[64][68];  // As[k][m]
    __shared__ float Bs[64][68];  // Bs[k][n]

    const int m0  = blockIdx.x * 64;
    const int n0  = blockIdx.y * 64;
    const int tid = threadIdx.x;

    const int lr = tid >> 4;
    const int lc = (tid & 15) << 2;

    int rows[4];
#pragma unroll
    for (int i = 0; i < 4; i++) rows[i] = xidx[m0 + lr + 16 * i];

    const int tm = (tid & 15) << 2;
    const int tn = (tid >> 4) << 2;

    float acc[4][4];
#pragma unroll
    for (int i = 0; i < 4; i++)
#pragma unroll
        for (int j = 0; j < 4; j++) acc[i][j] = 0.0f;

    for (int k0 = 0; k0 < DIM; k0 += 64) {
#pragma unroll
        for (int i = 0; i < 4; i++) {
            const int rl = lr + 16 * i;
            const float4 a = *(const float4*)&emb[(size_t)rows[i] * DIM + k0 + lc];
            As[lc + 0][rl] = a.x; As[lc + 1][rl] = a.y;
            As[lc + 2][rl] = a.z; As[lc + 3][rl] = a.w;
            const float4 b = *(const float4*)&W_ih[(size_t)(n0 + rl) * DIM + k0 + lc];
            Bs[lc + 0][rl] = b.x; Bs[lc + 1][rl] = b.y;
            Bs[lc + 2][rl] = b.z; Bs[lc + 3][rl] = b.w;
        }
        __syncthreads();
#pragma unroll 8
        for (int kk = 0; kk < 64; kk++) {
            const float4 a = *(const float4*)&As[kk][tm];
            const float4 b = *(const float4*)&Bs[kk][tn];
            acc[0][0] = fmaf(a.x, b.x, acc[0][0]);
            acc[0][1] = fmaf(a.x, b.y, acc[0][1]);
            acc[0][2] = fmaf(a.x, b.z, acc[0][2]);
            acc[0][3] = fmaf(a.x, b.w, acc[0][3]);
            acc[1][0] = fmaf(a.y, b.x, acc[1][0]);
            acc[1][1] = fmaf(a.y, b.y, acc[1][1]);
            acc[1][2] = fmaf(a.y, b.z, acc[1][2]);
            acc[1][3] = fmaf(a.y, b.w, acc[1][3]);
            acc[2][0] = fmaf(a.z, b.x, acc[2][0]);
            acc[2][1] = fmaf(a.z, b.y, acc[2][1]);
            acc[2][2] = fmaf(a.z, b.z, acc[2][2]);
            acc[2][3] = fmaf(a.z, b.w, acc[2][3]);
            acc[3][0] = fmaf(a.w, b.x, acc[3][0]);
            acc[3][1] = fmaf(a.w, b.y, acc[3][1]);
            acc[3][2] = fmaf(a.w, b.z, acc[3][2]);
            acc[3][3] = fmaf(a.w, b.w, acc[3][3]);
        }
        __syncthreads();
    }

    const int n = n0 + tn;
    const float bias0 = b_ih[n + 0] + b_hh[n + 0];
    const float bias1 = b_ih[n + 1] + b_hh[n + 1];
    const float bias2 = b_ih[n + 2] + b_hh[n + 2];
    const float bias3 = b_ih[n + 3] + b_hh[n + 3];
#pragma unroll
    for (int i = 0; i < 4; i++) {
        float4 o;
        o.x = acc[i][0] + bias0;
        o.y = acc[i][1] + bias1;
        o.z = acc[i][2] + bias2;
        o.w = acc[i][3] + bias3;
        *(float4*)&xp[(size_t)(m0 + tm + i) * DIM + n] = o;
    }
}

// ---------------------------------------------------------------------------
// Kernel 2: RNN scan, W column-split across CUs, LDS-resident.
//  bid = slice*GRP + grp  (group's 8 wgs at bids == grp mod 8 -> same XCD).
//  Thread (c = tid&63, ks = tid>>6): partial dot over 64 j's for 4 rows.
//  Per-step: LDS k-reduction -> tanh -> agent-scope h exchange (double-
//  buffered by t&1) + monotonic atomic counter barrier among 8 wgs.
// ---------------------------------------------------------------------------
__global__ __launch_bounds__(512)
void rnn_scan(const float4* __restrict__ Wpk, float* __restrict__ buf,
              float* __restrict__ hglob, int* __restrict__ cnt) {
    extern __shared__ float4 smem4[];
    float4* wlds = smem4;                       // [128*64] W slice
    float*  h4   = (float*)(smem4 + 8192);      // [4*512]  h rows
    float*  part = h4 + 2048;                   // [8*256]  k-partials

    const int tid   = threadIdx.x;
    const int slice = blockIdx.x / GRP;
    const int grp   = blockIdx.x % GRP;
    const int c     = tid & 63;
    const int ks    = tid >> 6;
    const int b0    = grp * RPG;
    const int col0  = slice * 64;

    // load W slice: wlds[jb*64 + cl] = Wpk[jb][col0+cl]
    for (int i = tid; i < 8192; i += 512) {
        const int jb = i >> 6, cl = i & 63;
        wlds[i] = Wpk[(size_t)jb * DIM + col0 + cl];
    }
    for (int i = tid; i < 2048; i += 512) h4[i] = 0.0f;
    __syncthreads();

    int* mycnt = cnt + grp;
    const float4* h4f4 = (const float4*)h4;
    const float4* wp   = wlds + ks * 16 * 64 + c;
    const int hb = ks * 16;

    for (int t = 0; t < SEQ; t++) {
        float p0 = 0.f, p1 = 0.f, p2 = 0.f, p3 = 0.f;
#pragma unroll
        for (int jb = 0; jb < 16; jb++) {
            const float4 w  = wp[jb * 64];
            const float4 h0 = h4f4[0 * 128 + hb + jb];
            const float4 h1 = h4f4[1 * 128 + hb + jb];
            const float4 h2 = h4f4[2 * 128 + hb + jb];
            const float4 h3 = h4f4[3 * 128 + hb + jb];
            p0 = fmaf(w.x, h0.x, p0); p0 = fmaf(w.y, h0.y, p0);
            p0 = fmaf(w.z, h0.z, p0); p0 = fmaf(w.w, h0.w, p0);
            p1 = fmaf(w.x, h1.x, p1); p1 = fmaf(w.y, h1.y, p1);
            p1 = fmaf(w.z, h1.z, p1); p1 = fmaf(w.w, h1.w, p1);
            p2 = fmaf(w.x, h2.x, p2); p2 = fmaf(w.y, h2.y, p2);
            p2 = fmaf(w.z, h2.z, p2); p2 = fmaf(w.w, h2.w, p2);
            p3 = fmaf(w.x, h3.x, p3); p3 = fmaf(w.y, h3.y, p3);
            p3 = fmaf(w.z, h3.z, p3); p3 = fmaf(w.w, h3.w, p3);
        }
        part[ks * 256 +   0 + c] = p0;
        part[ks * 256 +  64 + c] = p1;
        part[ks * 256 + 128 + c] = p2;
        part[ks * 256 + 192 + c] = p3;
        __syncthreads();

        float* hglw = hglob + ((size_t)(t & 1) * GRP + grp) * (RPG * DIM);
        if (tid < 256) {
            const int rr = tid >> 6;      // row 0..3
            const int cc = tid & 63;      // col local
            float s = part[0 * 256 + tid];
            s += part[1 * 256 + tid];
            s += part[2 * 256 + tid];
            s += part[3 * 256 + tid];
            s += part[4 * 256 + tid];
            s += part[5 * 256 + tid];
            s += part[6 * 256 + tid];
            s += part[7 * 256 + tid];
            const size_t boff = ((size_t)(b0 + rr) * SEQ + t) * DIM + col0 + cc;
            const float pre = buf[boff] + s;
            const float hn  = tanhf(pre);
            buf[boff] = hn;   // hidden state for softmax kernel
            __hip_atomic_store(&hglw[rr * DIM + col0 + cc], hn,
                               __ATOMIC_RELAXED, __HIP_MEMORY_SCOPE_AGENT);
        }
        __threadfence();          // each thread's stores device-visible
        __syncthreads();          // whole wg done before arrival

        if (t < SEQ - 1) {
            if (tid == 0) {
                __hip_atomic_fetch_add(mycnt, 1, __ATOMIC_RELEASE,
                                       __HIP_MEMORY_SCOPE_AGENT);
                const int target = CSL * (t + 1);
                while (__hip_atomic_load(mycnt, __ATOMIC_ACQUIRE,
                                         __HIP_MEMORY_SCOPE_AGENT) < target)
                    __builtin_amdgcn_s_sleep(2);
            }
            __syncthreads();
            // reload full h for this group's 4 rows (coalesced, L2-coherent)
#pragma unroll
            for (int p = 0; p < 4; p++)
                h4[p * DIM + tid] = __hip_atomic_load(&hglw[p * DIM + tid],
                                                      __ATOMIC_RELAXED,
                                                      __HIP_MEMORY_SCOPE_AGENT);
            __syncthreads();
        }
    }
}

// ---------------------------------------------------------------------------
// Kernel 3: softmax over H (per b,t) + transpose [B][T][H] -> out [B][H][T]
// ---------------------------------------------------------------------------
__global__ __launch_bounds__(256) void softmax_T(const float* __restrict__ hid,
                                                 float* __restrict__ out) {
    __shared__ float rowmax[64];
    __shared__ float rowinv[64];
    __shared__ float tile[64][65];

    const int b   = blockIdx.x;
    const int t0  = blockIdx.y * 64;
    const int tid = threadIdx.x;
    const float* base = hid + ((size_t)b * SEQ + t0) * DIM;

    const int r = tid >> 2;
    const int p = tid & 3;

    float m = -1e30f;
#pragma unroll 4
    for (int k = 0; k < 32; k++) {
        const float4 v = *(const float4*)&base[r * DIM + ((k * 4 + p) << 2)];
        m = fmaxf(m, fmaxf(fmaxf(v.x, v.y), fmaxf(v.z, v.w)));
    }
    m = fmaxf(m, __shfl_xor(m, 1));
    m = fmaxf(m, __shfl_xor(m, 2));

    float s = 0.0f;
#pragma unroll 4
    for (int k = 0; k < 32; k++) {
        const float4 v = *(const float4*)&base[r * DIM + ((k * 4 + p) << 2)];
        s += expf(v.x - m) + expf(v.y - m) + expf(v.z - m) + expf(v.w - m);
    }
    s += __shfl_xor(s, 1);
    s += __shfl_xor(s, 2);
    if (p == 0) {
        rowmax[r] = m;
        rowinv[r] = 1.0f / s;
    }
    __syncthreads();

    for (int hc = 0; hc < 8; hc++) {
#pragma unroll
        for (int i = 0; i < 16; i++) {
            const int lin = tid + 256 * i;
            const int rr  = lin >> 6;
            const int cc  = lin & 63;
            const float v = base[rr * DIM + hc * 64 + cc];
            tile[cc][rr] = expf(v - rowmax[rr]) * rowinv[rr];
        }
        __syncthreads();
#pragma unroll
        for (int i = 0; i < 16; i++) {
            const int lin = tid + 256 * i;
            const int hh  = lin >> 6;
            const int tt  = lin & 63;
            out[((size_t)b * DIM + hc * 64 + hh) * SEQ + t0 + tt] = tile[hh][tt];
        }
        __syncthreads();
    }
}

// ---------------------------------------------------------------------------
extern "C" void kernel_launch(void* const* d_in, const int* in_sizes, int n_in,
                              void* d_out, int out_size, void* d_ws, size_t ws_size,
                              hipStream_t stream) {
    const int*   x    = (const int*)  d_in[0];
    const float* emb  = (const float*)d_in[1];
    const float* W_ih = (const float*)d_in[2];
    const float* W_hh = (const float*)d_in[3];
    const float* b_ih = (const float*)d_in[4];
    const float* b_hh = (const float*)d_in[5];
    float* out = (float*)d_out;

    // 64 MB scratch: xp (then hid, in place) as [B][T][H]
    float* buf = (float*)d_ws;
    // staging inside d_out (16.7M floats); all consumed before softmax_T
    // overwrites d_out (stream-ordered):
    float4* Wpk   = (float4*)out;            // 1M floats
    float*  hglob = out + (4 << 20);         // 2*16*2048 floats = 64K
    int*    cnt   = (int*)(out + (8 << 20)); // 16 ints

    static bool attr_set = false;
    if (!attr_set) {
        hipFuncSetAttribute((const void*)rnn_scan,
                            hipFuncAttributeMaxDynamicSharedMemorySize,
                            RNN_LDS_BYTES);
        attr_set = true;
    }

    pack_w<<<dim3(DIM), 128, 0, stream>>>(W_hh, Wpk, cnt);
    embed_proj<<<dim3(MTOT / 64, DIM / 64), 256, 0, stream>>>(x, emb, W_ih, b_ih, b_hh, buf);
    rnn_scan<<<CSL * GRP, 512, RNN_LDS_BYTES, stream>>>(Wpk, buf, hglob, cnt);
    softmax_T<<<dim3(BATCH, SEQ / 64), 256, 0, stream>>>(buf, out);
}